// Round 8
// baseline (318.575 us; speedup 1.0000x reference)
//
#include <hip/hip_runtime.h>
#include <hip/hip_bf16.h>
#include <stdint.h>

#define NN 100000
#define KN 50
#define FIN 128
#define FOUT 128
#define BM 64
#define NB 782            // gather blocks (each owns 128 nodes), co-resident at 4/CU
#define RPB 128           // rows per gather block
#define NBIN 4
#define BINSZ 25000       // 25k nodes * 128B fp8 = 3.2 MB < 4 MB per-XCD L2

typedef __attribute__((ext_vector_type(8))) short bf16x8;
typedef __attribute__((ext_vector_type(4))) float f32x4;
typedef __attribute__((ext_vector_type(2))) float f32x2;

__device__ __forceinline__ uint16_t f2b(float f){
  uint32_t x = __builtin_bit_cast(uint32_t, f);
  x += 0x7fffu + ((x >> 16) & 1u);   // round-to-nearest-even
  return (uint16_t)(x >> 16);
}

// ---- prep: cast x fp32 -> fp8 e4m3 (HW cvt) for the gather path ----
__global__ void cast_fp8_kernel(const float* __restrict__ x, uint32_t* __restrict__ xf8){
  int i = blockIdx.x * blockDim.x + threadIdx.x;      // one u32 = 4 fp8
  float4 v = *(const float4*)(x + (size_t)i * 4);
  uint32_t p = 0;
  p = __builtin_amdgcn_cvt_pk_fp8_f32(v.x, v.y, p, false);
  p = __builtin_amdgcn_cvt_pk_fp8_f32(v.z, v.w, p, true);
  xf8[i] = p;
}

// ---- prep: pack weight [256][128] fp32 -> bf16 in MFMA B-fragment order ----
__global__ void pack_w_kernel(const float* __restrict__ w, uint16_t* __restrict__ wp){
  int kt = blockIdx.x >> 3, nt = blockIdx.x & 7;
  int lane = threadIdx.x;
  int col = nt * 16 + (lane & 15);
  int k0  = kt * 32 + ((lane >> 4) << 3);
  uint16_t vals[8];
  #pragma unroll
  for (int i = 0; i < 8; i++) vals[i] = f2b(w[(k0 + i) * FOUT + col]);
  *(uint4*)(wp + ((size_t)(kt * 8 + nt) * 64 + lane) * 8) = *(const uint4*)vals;
}

// ---- prep: detect int32 vs int64 neighbors layout (prefix scan is enough) ----
__global__ void detect_kernel(const int* __restrict__ nb, int* __restrict__ flag){
  int i = blockIdx.x * blockDim.x + threadIdx.x;   // 8192 odd words
  if (nb[2 * i + 1] != 0) *flag = 1;
}

#define CVT8(ACC, v)                                           \
  ACC[0] += __builtin_amdgcn_cvt_pk_f32_fp8((v).x, false);     \
  ACC[1] += __builtin_amdgcn_cvt_pk_f32_fp8((v).x, true);      \
  ACC[2] += __builtin_amdgcn_cvt_pk_f32_fp8((v).y, false);     \
  ACC[3] += __builtin_amdgcn_cvt_pk_f32_fp8((v).y, true);      \
  ACC[4] += __builtin_amdgcn_cvt_pk_f32_fp8((v).z, false);     \
  ACC[5] += __builtin_amdgcn_cvt_pk_f32_fp8((v).z, true);      \
  ACC[6] += __builtin_amdgcn_cvt_pk_f32_fp8((v).w, false);     \
  ACC[7] += __builtin_amdgcn_cvt_pk_f32_fp8((v).w, true);

#define PASS_ROW(ACC, RR) {                                              \
  int r = (wave << 5) + ((RR) << 3) + g;                                 \
  int k0 = off[r][p], k1 = off[r][p + 1];                                \
  for (int k = k0; k < k1; ++k){                                         \
    int j = srt[r][k];                                                   \
    uint4 v = *(const uint4*)(xf8 + ((size_t)(uint32_t)j << 7) + fl);    \
    CVT8(ACC, v);                                                        \
  } }

#define STORE_ROW(ACC, RR) {                                             \
  int r = (wave << 5) + ((RR) << 3) + g;                                 \
  int node = base + r;                                                   \
  if (node < NN){                                                        \
    uint16_t o[16];                                                      \
    _Pragma("unroll")                                                    \
    for (int i = 0; i < 8; i++){                                         \
      o[2*i]   = f2b(ACC[i].x * (1.0f / KN));                            \
      o[2*i+1] = f2b(ACC[i].y * (1.0f / KN));                            \
    }                                                                    \
    uint16_t* dst = agg + (size_t)node * FIN + fl;                       \
    *(uint4*)(dst)     = *(const uint4*)(o);                             \
    *(uint4*)(dst + 8) = *(const uint4*)(o + 8);                         \
  } }

// ---- gather+mean: bin-phased for per-XCD L2 residency, soft grid barrier ----
// All 782 blocks are co-resident (LDS 28.9KB*4<160KB, 4 waves*4<=32, VGPR<=128).
// Between barriers every block gathers only source rows in bin p (3.2MB -> L2-hit).
// Barrier is best-effort: correctness NEVER depends on it (bounded spin).
__global__ __launch_bounds__(256, 4) void gather_kernel(
    const uint8_t* __restrict__ xf8,
    const int* __restrict__ nbrs,
    const int* __restrict__ flag,
    uint16_t* __restrict__ agg,
    int* __restrict__ bar)
{
  __shared__ int    srt[RPB][KN];        // 25.6 KB bin-sorted indices
  __shared__ int    cnt[RPB][NBIN];      // 2 KB
  __shared__ ushort off[RPB][NBIN + 1];  // 1.25 KB
  const int tid  = threadIdx.x;
  const int wave = tid >> 6, lane = tid & 63;
  const int base = blockIdx.x * RPB;
  const int sm = (*flag != 0) ? 1 : 2;

  for (int t = tid; t < RPB * NBIN; t += 256) ((int*)cnt)[t] = 0;
  __syncthreads();

  // phase A: per-row bin histogram (coalesced nbrs read)
  for (int e = tid; e < RPB * KN; e += 256){
    int r = e / KN, c = e - r * KN;
    int node = base + r; if (node >= NN) node = NN - 1;
    int j = nbrs[(node * KN + c) * sm];
    atomicAdd(&cnt[r][j / BINSZ], 1);
  }
  __syncthreads();
  if (tid < RPB){
    int s = 0;
    #pragma unroll
    for (int p = 0; p < NBIN; ++p){ off[tid][p] = (ushort)s; s += cnt[tid][p]; }
    off[tid][NBIN] = (ushort)s;
  }
  __syncthreads();
  // phase B: deterministic scatter, one thread per row, packed register cursors
  if (tid < RPB){
    int node = base + tid; if (node >= NN) node = NN - 1;
    unsigned long long cur = 0;
    #pragma unroll
    for (int p = 0; p < NBIN; ++p)
      cur |= (unsigned long long)off[tid][p] << (16 * p);
    for (int k = 0; k < KN; ++k){
      int j = nbrs[(node * KN + k) * sm];    // L2-warm re-read
      int b = j / BINSZ;
      int pos = (int)((cur >> (16 * b)) & 0xffffULL);
      cur += 1ULL << (16 * b);
      srt[tid][pos] = j;
    }
  }
  __syncthreads();

  const int g  = lane >> 3;                  // 8 groups of 8 lanes
  const int fl = (lane & 7) * 16;            // 16 fp8 features per lane
  f32x2 acc0[8], acc1[8], acc2[8], acc3[8];
  #pragma unroll
  for (int i = 0; i < 8; i++){
    acc0[i] = (f32x2){0.f, 0.f}; acc1[i] = (f32x2){0.f, 0.f};
    acc2[i] = (f32x2){0.f, 0.f}; acc3[i] = (f32x2){0.f, 0.f};
  }

  for (int p = 0; p < NBIN; ++p){
    if (p){                                  // soft grid barrier (best-effort)
      __syncthreads();
      if (tid == 0){
        atomicAdd(bar, 1);                   // device-scope
        int tgt = NB * p, it = 0;
        while (__hip_atomic_load(bar, __ATOMIC_RELAXED, __HIP_MEMORY_SCOPE_AGENT) < tgt
               && it < 20000){ __builtin_amdgcn_s_sleep(1); ++it; }
      }
      __syncthreads();
    }
    PASS_ROW(acc0, 0)
    PASS_ROW(acc1, 1)
    PASS_ROW(acc2, 2)
    PASS_ROW(acc3, 3)
  }

  STORE_ROW(acc0, 0)
  STORE_ROW(acc1, 1)
  STORE_ROW(acc2, 2)
  STORE_ROW(acc3, 3)
}

// ---- GEMM: concat(x, agg) @ W + b, relu ----
__global__ __launch_bounds__(256) void gemm_kernel(
    const float* __restrict__ x,
    const uint16_t* __restrict__ agg,
    const uint16_t* __restrict__ wp,
    const float* __restrict__ bias,
    float* __restrict__ out)
{
  __shared__ uint16_t h[BM][264];            // 33792 B
  const int tid  = threadIdx.x;
  const int wave = tid >> 6, lane = tid & 63;
  const int base = blockIdx.x * BM;

  #pragma unroll
  for (int jj = 0; jj < 8; jj++){
    int ci = jj * 256 + tid;
    int r = ci >> 5, c = ci & 31;
    int node = base + r; if (node >= NN) node = NN - 1;
    float4 v = *(const float4*)(x + (size_t)node * FIN + c * 4);
    ushort4 o2; o2.x = f2b(v.x); o2.y = f2b(v.y); o2.z = f2b(v.z); o2.w = f2b(v.w);
    *(ushort4*)(&h[r][c * 4]) = o2;
  }
  #pragma unroll
  for (int jj = 0; jj < 4; jj++){
    int ci = jj * 256 + tid;
    int r = ci >> 4, c = ci & 15;
    int node = base + r; if (node >= NN) node = NN - 1;
    uint4 v = *(const uint4*)(agg + (size_t)node * FIN + c * 8);
    *(uint4*)(&h[r][FIN + c * 8]) = v;
  }

  bf16x8 bfr[8][2];
  #pragma unroll
  for (int kt = 0; kt < 8; kt++)
    #pragma unroll
    for (int ntl = 0; ntl < 2; ntl++){
      int nt = wave * 2 + ntl;
      bfr[kt][ntl] = *(const bf16x8*)(wp + ((size_t)(kt * 8 + nt) * 64 + lane) * 8);
    }

  __syncthreads();

  f32x4 acc[4][2];
  #pragma unroll
  for (int mt = 0; mt < 4; mt++)
    for (int n = 0; n < 2; n++) acc[mt][n] = (f32x4){0.f, 0.f, 0.f, 0.f};

  const int arow = lane & 15;
  const int ak   = (lane >> 4) << 3;
  #pragma unroll
  for (int kt = 0; kt < 8; kt++){
    #pragma unroll
    for (int mt = 0; mt < 4; mt++){
      bf16x8 af = *(const bf16x8*)(&h[mt * 16 + arow][kt * 32 + ak]);
      acc[mt][0] = __builtin_amdgcn_mfma_f32_16x16x32_bf16(af, bfr[kt][0], acc[mt][0], 0, 0, 0);
      acc[mt][1] = __builtin_amdgcn_mfma_f32_16x16x32_bf16(af, bfr[kt][1], acc[mt][1], 0, 0, 0);
    }
  }

  #pragma unroll
  for (int ntl = 0; ntl < 2; ntl++){
    int col = wave * 32 + ntl * 16 + (lane & 15);
    float bv = bias[col];
    #pragma unroll
    for (int mt = 0; mt < 4; mt++){
      #pragma unroll
      for (int i = 0; i < 4; i++){
        int row = mt * 16 + ((lane >> 4) << 2) + i;
        int node = base + row;
        if (node < NN){
          float v = acc[mt][ntl][i] + bv;
          out[(size_t)node * FOUT + col] = fmaxf(v, 0.f);
        }
      }
    }
  }
}

extern "C" void kernel_launch(void* const* d_in, const int* in_sizes, int n_in,
                              void* d_out, int out_size, void* d_ws, size_t ws_size,
                              hipStream_t stream){
  const float* x    = (const float*)d_in[0];
  const int*   nbrs = (const int*)d_in[1];
  const float* w    = (const float*)d_in[2];
  const float* bias = (const float*)d_in[3];
  float* out = (float*)d_out;

  uint8_t*  xf8  = (uint8_t*)d_ws;                                        // 12.8 MB
  uint16_t* wp   = (uint16_t*)((char*)d_ws + (size_t)NN * FIN);           // 64 KB
  int*      flag = (int*)((char*)d_ws + (size_t)NN * FIN + 65536);
  int*      bar  = flag + 1;
  uint16_t* agg  = (uint16_t*)((char*)d_ws + (size_t)NN * FIN + 131072);  // 25.6 MB

  (void)hipMemsetAsync(flag, 0, 8, stream);   // zeroes flag + bar
  cast_fp8_kernel<<<NN * FIN / 4 / 256, 256, 0, stream>>>(x, (uint32_t*)xf8);
  pack_w_kernel<<<64, 64, 0, stream>>>(w, wp);
  detect_kernel<<<32, 256, 0, stream>>>(nbrs, flag);
  gather_kernel<<<NB, 256, 0, stream>>>(xf8, nbrs, flag, agg, bar);
  gemm_kernel<<<(NN + BM - 1) / BM, 256, 0, stream>>>(x, agg, wp, bias, out);
}

// Round 9
// 206.461 us; speedup vs baseline: 1.5430x; 1.5430x over previous
//
#include <hip/hip_runtime.h>
#include <hip/hip_bf16.h>
#include <stdint.h>

#define NN 100000
#define KN 50
#define FIN 128
#define FOUT 128
#define BM 64
#define NBIN 4
#define BINSZ 25000        // 25k fp8 rows = 3.2 MB < 4 MB per-XCD L2

typedef __attribute__((ext_vector_type(8))) short bf16x8;
typedef __attribute__((ext_vector_type(4))) float f32x4;
typedef __attribute__((ext_vector_type(2))) float f32x2;

__device__ __forceinline__ uint16_t f2b(float f){
  uint32_t x = __builtin_bit_cast(uint32_t, f);
  x += 0x7fffu + ((x >> 16) & 1u);   // round-to-nearest-even
  return (uint16_t)(x >> 16);
}

// ---- prep: cast x fp32 -> fp8 e4m3 (HW cvt) for the gather path ----
__global__ void cast_fp8_kernel(const float* __restrict__ x, uint32_t* __restrict__ xf8){
  int i = blockIdx.x * blockDim.x + threadIdx.x;      // one u32 = 4 fp8
  float4 v = *(const float4*)(x + (size_t)i * 4);
  uint32_t p = 0;
  p = __builtin_amdgcn_cvt_pk_fp8_f32(v.x, v.y, p, false);
  p = __builtin_amdgcn_cvt_pk_fp8_f32(v.z, v.w, p, true);
  xf8[i] = p;
}

// ---- prep: pack weight [256][128] fp32 -> bf16 in MFMA B-fragment order ----
__global__ void pack_w_kernel(const float* __restrict__ w, uint16_t* __restrict__ wp){
  int kt = blockIdx.x >> 3, nt = blockIdx.x & 7;
  int lane = threadIdx.x;
  int col = nt * 16 + (lane & 15);
  int k0  = kt * 32 + ((lane >> 4) << 3);
  uint16_t vals[8];
  #pragma unroll
  for (int i = 0; i < 8; i++) vals[i] = f2b(w[(k0 + i) * FOUT + col]);
  *(uint4*)(wp + ((size_t)(kt * 8 + nt) * 64 + lane) * 8) = *(const uint4*)vals;
}

// ---- prep: detect int32 vs int64 neighbors layout (prefix scan is enough) ----
__global__ void detect_kernel(const int* __restrict__ nb, int* __restrict__ flag){
  int i = blockIdx.x * blockDim.x + threadIdx.x;   // 8192 odd words
  if (nb[2 * i + 1] != 0) *flag = 1;
}

// ---- gather+mean: r4 structure + 4 bin-phased scans (no sort, no barrier) ----
// Pass p loads only neighbors in [p*25k,(p+1)*25k): concurrent blocks touch a
// 3.2 MB slice that fits every XCD's 4 MB L2. Phase alignment is best-effort
// via natural co-scheduling; worst case degrades to the r4 access pattern.
__global__ __launch_bounds__(256) void gather_kernel(
    const uint8_t* __restrict__ xf8,
    const int* __restrict__ nbrs,
    const int* __restrict__ flag,
    uint16_t* __restrict__ agg)
{
  __shared__ int idxs[4][8 * KN];            // 6400 B
  const int tid  = threadIdx.x;
  const int wave = tid >> 6, lane = tid & 63;
  const int base = blockIdx.x * 32;          // 32 nodes per block, 8 per wave
  const int stride_mul = (*flag != 0) ? 1 : 2;

  // stage this wave's 8 rows x 50 neighbor indices
  {
    long long fb = (long long)(base + wave * 8) * KN;
    for (int t = lane; t < 8 * KN; t += 64)
      idxs[wave][t] = nbrs[(fb + t) * stride_mul];
  }
  __syncthreads();

  const int g  = lane >> 3;                  // 8 groups of 8 lanes
  const int fl = (lane & 7) * 16;            // 16 fp8 features per lane
  const int node = base + wave * 8 + g;
  const int* ip = &idxs[wave][g * KN];

  f32x2 acc[8];
  #pragma unroll
  for (int i = 0; i < 8; i++) acc[i] = (f32x2){0.f, 0.f};

  #pragma unroll 1
  for (int p = 0; p < NBIN; ++p){
    const unsigned lo = (unsigned)(p * BINSZ);
    #pragma unroll 10
    for (int k = 0; k < KN; k++){
      int j = ip[k];                         // ds_read broadcast within group
      if ((unsigned)j - lo < (unsigned)BINSZ){
        uint4 v = *(const uint4*)(xf8 + ((size_t)(uint32_t)j << 7) + fl);
        acc[0] += __builtin_amdgcn_cvt_pk_f32_fp8(v.x, false);
        acc[1] += __builtin_amdgcn_cvt_pk_f32_fp8(v.x, true);
        acc[2] += __builtin_amdgcn_cvt_pk_f32_fp8(v.y, false);
        acc[3] += __builtin_amdgcn_cvt_pk_f32_fp8(v.y, true);
        acc[4] += __builtin_amdgcn_cvt_pk_f32_fp8(v.z, false);
        acc[5] += __builtin_amdgcn_cvt_pk_f32_fp8(v.z, true);
        acc[6] += __builtin_amdgcn_cvt_pk_f32_fp8(v.w, false);
        acc[7] += __builtin_amdgcn_cvt_pk_f32_fp8(v.w, true);
      }
    }
  }

  uint16_t o[16];
  #pragma unroll
  for (int i = 0; i < 8; i++){
    o[2*i]   = f2b(acc[i].x * (1.0f / KN));
    o[2*i+1] = f2b(acc[i].y * (1.0f / KN));
  }
  uint16_t* dst = agg + (size_t)node * FIN + fl;   // fl doubles as bf16 elem offset
  *(uint4*)(dst)     = *(const uint4*)(o);
  *(uint4*)(dst + 8) = *(const uint4*)(o + 8);
}

// ---- GEMM: concat(x, agg) @ W + b, relu ----
__global__ __launch_bounds__(256) void gemm_kernel(
    const float* __restrict__ x,
    const uint16_t* __restrict__ agg,
    const uint16_t* __restrict__ wp,
    const float* __restrict__ bias,
    float* __restrict__ out)
{
  __shared__ uint16_t h[BM][264];            // 33792 B
  const int tid  = threadIdx.x;
  const int wave = tid >> 6, lane = tid & 63;
  const int base = blockIdx.x * BM;

  // self features: x fp32 -> bf16 -> h[r][0..128)
  #pragma unroll
  for (int jj = 0; jj < 8; jj++){
    int ci = jj * 256 + tid;                 // 2048 float4 chunks
    int r = ci >> 5, c = ci & 31;
    int node = base + r; if (node >= NN) node = NN - 1;
    float4 v = *(const float4*)(x + (size_t)node * FIN + c * 4);
    ushort4 o2; o2.x = f2b(v.x); o2.y = f2b(v.y); o2.z = f2b(v.z); o2.w = f2b(v.w);
    *(ushort4*)(&h[r][c * 4]) = o2;
  }
  // aggregated features: bf16 copy -> h[r][128..256)
  #pragma unroll
  for (int jj = 0; jj < 4; jj++){
    int ci = jj * 256 + tid;                 // 1024 uint4 chunks
    int r = ci >> 4, c = ci & 15;
    int node = base + r; if (node >= NN) node = NN - 1;
    uint4 v = *(const uint4*)(agg + (size_t)node * FIN + c * 8);
    *(uint4*)(&h[r][FIN + c * 8]) = v;
  }

  // B fragments: wave w owns cols [w*32, w*32+32)
  bf16x8 bfr[8][2];
  #pragma unroll
  for (int kt = 0; kt < 8; kt++)
    #pragma unroll
    for (int ntl = 0; ntl < 2; ntl++){
      int nt = wave * 2 + ntl;
      bfr[kt][ntl] = *(const bf16x8*)(wp + ((size_t)(kt * 8 + nt) * 64 + lane) * 8);
    }

  __syncthreads();

  f32x4 acc[4][2];
  #pragma unroll
  for (int mt = 0; mt < 4; mt++)
    for (int n = 0; n < 2; n++) acc[mt][n] = (f32x4){0.f, 0.f, 0.f, 0.f};

  const int arow = lane & 15;
  const int ak   = (lane >> 4) << 3;
  #pragma unroll
  for (int kt = 0; kt < 8; kt++){
    #pragma unroll
    for (int mt = 0; mt < 4; mt++){
      bf16x8 af = *(const bf16x8*)(&h[mt * 16 + arow][kt * 32 + ak]);
      acc[mt][0] = __builtin_amdgcn_mfma_f32_16x16x32_bf16(af, bfr[kt][0], acc[mt][0], 0, 0, 0);
      acc[mt][1] = __builtin_amdgcn_mfma_f32_16x16x32_bf16(af, bfr[kt][1], acc[mt][1], 0, 0, 0);
    }
  }

  // epilogue: C/D layout col=lane&15, row=(lane>>4)*4+i  [m89]
  #pragma unroll
  for (int ntl = 0; ntl < 2; ntl++){
    int col = wave * 32 + ntl * 16 + (lane & 15);
    float bv = bias[col];
    #pragma unroll
    for (int mt = 0; mt < 4; mt++){
      #pragma unroll
      for (int i = 0; i < 4; i++){
        int row = mt * 16 + ((lane >> 4) << 2) + i;
        int node = base + row;
        if (node < NN){
          float v = acc[mt][ntl][i] + bv;
          out[(size_t)node * FOUT + col] = fmaxf(v, 0.f);
        }
      }
    }
  }
}

extern "C" void kernel_launch(void* const* d_in, const int* in_sizes, int n_in,
                              void* d_out, int out_size, void* d_ws, size_t ws_size,
                              hipStream_t stream){
  const float* x    = (const float*)d_in[0];
  const int*   nbrs = (const int*)d_in[1];
  const float* w    = (const float*)d_in[2];
  const float* bias = (const float*)d_in[3];
  float* out = (float*)d_out;

  uint8_t*  xf8  = (uint8_t*)d_ws;                                        // 12.8 MB
  uint16_t* wp   = (uint16_t*)((char*)d_ws + (size_t)NN * FIN);           // 64 KB
  int*      flag = (int*)((char*)d_ws + (size_t)NN * FIN + 65536);
  uint16_t* agg  = (uint16_t*)((char*)d_ws + (size_t)NN * FIN + 131072);  // 25.6 MB

  (void)hipMemsetAsync(flag, 0, 4, stream);
  cast_fp8_kernel<<<NN * FIN / 4 / 256, 256, 0, stream>>>(x, (uint32_t*)xf8);
  pack_w_kernel<<<64, 64, 0, stream>>>(w, wp);
  detect_kernel<<<32, 256, 0, stream>>>(nbrs, flag);
  gather_kernel<<<NN / 32, 256, 0, stream>>>(xf8, nbrs, flag, agg);
  gemm_kernel<<<(NN + BM - 1) / BM, 256, 0, stream>>>(x, agg, wp, bias, out);
}

// Round 10
// 173.303 us; speedup vs baseline: 1.8383x; 1.1913x over previous
//
#include <hip/hip_runtime.h>
#include <hip/hip_bf16.h>
#include <stdint.h>

#define NN 100000
#define KN 50
#define FIN 128
#define FOUT 128
#define BM 64
#define BINSZ 25000        // 25k fp8 rows = 3.2 MB < 4 MB per-XCD L2

typedef __attribute__((ext_vector_type(8))) short bf16x8;
typedef __attribute__((ext_vector_type(4))) float f32x4;
typedef __attribute__((ext_vector_type(2))) float f32x2;

__device__ __forceinline__ uint16_t f2b(float f){
  uint32_t x = __builtin_bit_cast(uint32_t, f);
  x += 0x7fffu + ((x >> 16) & 1u);   // round-to-nearest-even
  return (uint16_t)(x >> 16);
}

// ---- prep: cast x fp32 -> fp8 e4m3 (HW cvt) for the gather path ----
__global__ void cast_fp8_kernel(const float* __restrict__ x, uint32_t* __restrict__ xf8){
  int i = blockIdx.x * blockDim.x + threadIdx.x;      // one u32 = 4 fp8
  float4 v = *(const float4*)(x + (size_t)i * 4);
  uint32_t p = 0;
  p = __builtin_amdgcn_cvt_pk_fp8_f32(v.x, v.y, p, false);
  p = __builtin_amdgcn_cvt_pk_fp8_f32(v.z, v.w, p, true);
  xf8[i] = p;
}

// ---- prep: pack weight [256][128] fp32 -> bf16 in MFMA B-fragment order ----
__global__ void pack_w_kernel(const float* __restrict__ w, uint16_t* __restrict__ wp){
  int kt = blockIdx.x >> 3, nt = blockIdx.x & 7;
  int lane = threadIdx.x;
  int col = nt * 16 + (lane & 15);
  int k0  = kt * 32 + ((lane >> 4) << 3);
  uint16_t vals[8];
  #pragma unroll
  for (int i = 0; i < 8; i++) vals[i] = f2b(w[(k0 + i) * FOUT + col]);
  *(uint4*)(wp + ((size_t)(kt * 8 + nt) * 64 + lane) * 8) = *(const uint4*)vals;
}

// ---- prep: detect int32 vs int64 neighbors layout (prefix scan is enough) ----
__global__ void detect_kernel(const int* __restrict__ nb, int* __restrict__ flag){
  int i = blockIdx.x * blockDim.x + threadIdx.x;   // 8192 odd words
  if (nb[2 * i + 1] != 0) *flag = 1;
}

// ---- prep: per-node 4-bin counting sort of neighbor indices ----
// One thread per node; two register-cursor passes, no atomics. Output order is
// bin-phased so the gather's access stream is L2-slice-resident per phase.
__global__ __launch_bounds__(256) void sort_kernel(
    const int* __restrict__ nbrs,
    const int* __restrict__ flag,
    int* __restrict__ srt,
    uint32_t* __restrict__ offs)
{
  int node = blockIdx.x * blockDim.x + threadIdx.x;
  if (node >= NN) return;
  const int sm = (*flag != 0) ? 1 : 2;
  const int rb = node * KN;

  int c0 = 0, c1 = 0, c2 = 0;
  #pragma unroll 10
  for (int k = 0; k < KN; ++k){
    int j = nbrs[(rb + k) * sm];
    c0 += (j < BINSZ);
    c1 += (j < 2 * BINSZ);
    c2 += (j < 3 * BINSZ);
  }
  // c0..c2 are cumulative counts; offsets o1=c0, o2=c1, o3=c2
  offs[node] = (uint32_t)c0 | ((uint32_t)c1 << 8) | ((uint32_t)c2 << 16);

  uint64_t cur = ((uint64_t)c2 << 48) | ((uint64_t)c1 << 32) | ((uint64_t)c0 << 16);
  for (int k = 0; k < KN; ++k){
    int j = nbrs[(rb + k) * sm];           // L1-warm re-read
    int b = (j >= BINSZ) + (j >= 2 * BINSZ) + (j >= 3 * BINSZ);
    int pos = (int)((cur >> (16 * b)) & 0xffffULL);
    cur += 1ULL << (16 * b);
    srt[rb + pos] = j;
  }
}

#define CVT8(v)                                              \
  acc[0] += __builtin_amdgcn_cvt_pk_f32_fp8((v).x, false);   \
  acc[1] += __builtin_amdgcn_cvt_pk_f32_fp8((v).x, true);    \
  acc[2] += __builtin_amdgcn_cvt_pk_f32_fp8((v).y, false);   \
  acc[3] += __builtin_amdgcn_cvt_pk_f32_fp8((v).y, true);    \
  acc[4] += __builtin_amdgcn_cvt_pk_f32_fp8((v).z, false);   \
  acc[5] += __builtin_amdgcn_cvt_pk_f32_fp8((v).z, true);    \
  acc[6] += __builtin_amdgcn_cvt_pk_f32_fp8((v).w, false);   \
  acc[7] += __builtin_amdgcn_cvt_pk_f32_fp8((v).w, true);

#define PASS(A, B)                                                        \
  for (int k = (A); k < (B); ++k){                                        \
    int j = ip[k];                                                        \
    uint4 v = *(const uint4*)(xf8 + ((size_t)(uint32_t)j << 7) + fl);     \
    CVT8(v);                                                              \
  }

// ---- gather+mean: r4 structure over presorted lists -> 4 L2-resident phases ----
__global__ __launch_bounds__(256) void gather_kernel(
    const uint8_t* __restrict__ xf8,
    const int* __restrict__ srt,
    const uint32_t* __restrict__ offs,
    uint16_t* __restrict__ agg)
{
  __shared__ int idxs[4][8 * KN];            // 6400 B
  const int tid  = threadIdx.x;
  const int wave = tid >> 6, lane = tid & 63;
  const int base = blockIdx.x * 32;          // 32 nodes per block, 8 per wave

  // stage this wave's 8 rows x 50 sorted indices (coalesced int32 reads)
  {
    int fb = (base + wave * 8) * KN;
    for (int t = lane; t < 8 * KN; t += 64)
      idxs[wave][t] = srt[fb + t];
  }
  __syncthreads();

  const int g  = lane >> 3;                  // 8 groups of 8 lanes
  const int fl = (lane & 7) * 16;            // 16 fp8 features per lane
  const int node = base + wave * 8 + g;
  const int* ip = &idxs[wave][g * KN];

  const uint32_t ow = offs[node];
  const int o1 = ow & 0xff, o2 = (ow >> 8) & 0xff, o3 = (ow >> 16) & 0xff;

  f32x2 acc[8];
  #pragma unroll
  for (int i = 0; i < 8; i++) acc[i] = (f32x2){0.f, 0.f};

  PASS(0,  o1)
  PASS(o1, o2)
  PASS(o2, o3)
  PASS(o3, KN)

  uint16_t o[16];
  #pragma unroll
  for (int i = 0; i < 8; i++){
    o[2*i]   = f2b(acc[i].x * (1.0f / KN));
    o[2*i+1] = f2b(acc[i].y * (1.0f / KN));
  }
  uint16_t* dst = agg + (size_t)node * FIN + fl;   // fl doubles as bf16 elem offset
  *(uint4*)(dst)     = *(const uint4*)(o);
  *(uint4*)(dst + 8) = *(const uint4*)(o + 8);
}

// ---- GEMM: concat(x, agg) @ W + b, relu ----
__global__ __launch_bounds__(256) void gemm_kernel(
    const float* __restrict__ x,
    const uint16_t* __restrict__ agg,
    const uint16_t* __restrict__ wp,
    const float* __restrict__ bias,
    float* __restrict__ out)
{
  __shared__ uint16_t h[BM][264];            // 33792 B
  const int tid  = threadIdx.x;
  const int wave = tid >> 6, lane = tid & 63;
  const int base = blockIdx.x * BM;

  // self features: x fp32 -> bf16 -> h[r][0..128)
  #pragma unroll
  for (int jj = 0; jj < 8; jj++){
    int ci = jj * 256 + tid;                 // 2048 float4 chunks
    int r = ci >> 5, c = ci & 31;
    int node = base + r; if (node >= NN) node = NN - 1;
    float4 v = *(const float4*)(x + (size_t)node * FIN + c * 4);
    ushort4 o2; o2.x = f2b(v.x); o2.y = f2b(v.y); o2.z = f2b(v.z); o2.w = f2b(v.w);
    *(ushort4*)(&h[r][c * 4]) = o2;
  }
  // aggregated features: bf16 copy -> h[r][128..256)
  #pragma unroll
  for (int jj = 0; jj < 4; jj++){
    int ci = jj * 256 + tid;                 // 1024 uint4 chunks
    int r = ci >> 4, c = ci & 15;
    int node = base + r; if (node >= NN) node = NN - 1;
    uint4 v = *(const uint4*)(agg + (size_t)node * FIN + c * 8);
    *(uint4*)(&h[r][FIN + c * 8]) = v;
  }

  // B fragments: wave w owns cols [w*32, w*32+32)
  bf16x8 bfr[8][2];
  #pragma unroll
  for (int kt = 0; kt < 8; kt++)
    #pragma unroll
    for (int ntl = 0; ntl < 2; ntl++){
      int nt = wave * 2 + ntl;
      bfr[kt][ntl] = *(const bf16x8*)(wp + ((size_t)(kt * 8 + nt) * 64 + lane) * 8);
    }

  __syncthreads();

  f32x4 acc[4][2];
  #pragma unroll
  for (int mt = 0; mt < 4; mt++)
    for (int n = 0; n < 2; n++) acc[mt][n] = (f32x4){0.f, 0.f, 0.f, 0.f};

  const int arow = lane & 15;
  const int ak   = (lane >> 4) << 3;
  #pragma unroll
  for (int kt = 0; kt < 8; kt++){
    #pragma unroll
    for (int mt = 0; mt < 4; mt++){
      bf16x8 af = *(const bf16x8*)(&h[mt * 16 + arow][kt * 32 + ak]);
      acc[mt][0] = __builtin_amdgcn_mfma_f32_16x16x32_bf16(af, bfr[kt][0], acc[mt][0], 0, 0, 0);
      acc[mt][1] = __builtin_amdgcn_mfma_f32_16x16x32_bf16(af, bfr[kt][1], acc[mt][1], 0, 0, 0);
    }
  }

  // epilogue: C/D layout col=lane&15, row=(lane>>4)*4+i  [m89]
  #pragma unroll
  for (int ntl = 0; ntl < 2; ntl++){
    int col = wave * 32 + ntl * 16 + (lane & 15);
    float bv = bias[col];
    #pragma unroll
    for (int mt = 0; mt < 4; mt++){
      #pragma unroll
      for (int i = 0; i < 4; i++){
        int row = mt * 16 + ((lane >> 4) << 2) + i;
        int node = base + row;
        if (node < NN){
          float v = acc[mt][ntl][i] + bv;
          out[(size_t)node * FOUT + col] = fmaxf(v, 0.f);
        }
      }
    }
  }
}

extern "C" void kernel_launch(void* const* d_in, const int* in_sizes, int n_in,
                              void* d_out, int out_size, void* d_ws, size_t ws_size,
                              hipStream_t stream){
  const float* x    = (const float*)d_in[0];
  const int*   nbrs = (const int*)d_in[1];
  const float* w    = (const float*)d_in[2];
  const float* bias = (const float*)d_in[3];
  float* out = (float*)d_out;

  char* p = (char*)d_ws;
  uint8_t*  xf8  = (uint8_t*)p;            p += (size_t)NN * FIN;        // 12.8 MB
  uint16_t* wp   = (uint16_t*)p;           p += 65536;                   // 64 KB
  int*      flag = (int*)p;                p += 4096;
  uint16_t* agg  = (uint16_t*)p;           p += (size_t)NN * FIN * 2;    // 25.6 MB
  int*      srt  = (int*)p;                p += (size_t)NN * KN * 4;     // 20 MB
  uint32_t* offs = (uint32_t*)p;                                          // 400 KB

  (void)hipMemsetAsync(flag, 0, 4, stream);
  cast_fp8_kernel<<<NN * FIN / 4 / 256, 256, 0, stream>>>(x, (uint32_t*)xf8);
  pack_w_kernel<<<64, 64, 0, stream>>>(w, wp);
  detect_kernel<<<32, 256, 0, stream>>>(nbrs, flag);
  sort_kernel<<<(NN + 255) / 256, 256, 0, stream>>>(nbrs, flag, srt, offs);
  gather_kernel<<<NN / 32, 256, 0, stream>>>(xf8, srt, offs, agg);
  gemm_kernel<<<(NN + BM - 1) / BM, 256, 0, stream>>>(x, agg, wp, bias, out);
}

// Round 11
// 123.327 us; speedup vs baseline: 2.5832x; 1.4052x over previous
//
#include <hip/hip_runtime.h>
#include <hip/hip_bf16.h>
#include <stdint.h>

#define NN 100000
#define KN 50
#define FIN 128
#define FOUT 128
#define BM 64

typedef __attribute__((ext_vector_type(8))) short bf16x8;
typedef __attribute__((ext_vector_type(4))) float f32x4;
typedef __attribute__((ext_vector_type(2))) float f32x2;
typedef __attribute__((ext_vector_type(4))) unsigned int u32x4;

__device__ __forceinline__ uint16_t f2b(float f){
  uint32_t x = __builtin_bit_cast(uint32_t, f);
  x += 0x7fffu + ((x >> 16) & 1u);   // round-to-nearest-even
  return (uint16_t)(x >> 16);
}

// ---- prep: cast x fp32 -> fp8 e4m3 (HW cvt) for the gather path ----
__global__ void cast_fp8_kernel(const float* __restrict__ x, uint32_t* __restrict__ xf8){
  int i = blockIdx.x * blockDim.x + threadIdx.x;      // one u32 = 4 fp8
  float4 v = *(const float4*)(x + (size_t)i * 4);
  uint32_t p = 0;
  p = __builtin_amdgcn_cvt_pk_fp8_f32(v.x, v.y, p, false);
  p = __builtin_amdgcn_cvt_pk_fp8_f32(v.z, v.w, p, true);
  xf8[i] = p;
}

// ---- prep: pack weight [256][128] fp32 -> bf16 in MFMA B-fragment order ----
__global__ void pack_w_kernel(const float* __restrict__ w, uint16_t* __restrict__ wp){
  int kt = blockIdx.x >> 3, nt = blockIdx.x & 7;
  int lane = threadIdx.x;
  int col = nt * 16 + (lane & 15);
  int k0  = kt * 32 + ((lane >> 4) << 3);
  uint16_t vals[8];
  #pragma unroll
  for (int i = 0; i < 8; i++) vals[i] = f2b(w[(k0 + i) * FOUT + col]);
  *(uint4*)(wp + ((size_t)(kt * 8 + nt) * 64 + lane) * 8) = *(const uint4*)vals;
}

// ---- prep: detect int32 vs int64 neighbors layout (prefix scan is enough) ----
__global__ void detect_kernel(const int* __restrict__ nb, int* __restrict__ flag){
  int i = blockIdx.x * blockDim.x + threadIdx.x;   // 8192 odd words
  if (nb[2 * i + 1] != 0) *flag = 1;
}

// sc0 = L1-bypass, L2-allowed load (glc successor on gfx950)
#define GLOAD(B, K) { \
  const uint8_t* a_ = xfl + ((size_t)(uint32_t)ip[K] << 7); \
  asm volatile("global_load_dwordx4 %0, %1, off sc0" : "=v"(B) : "v"(a_)); }

// counted-vmcnt wait tied to B via "+v": SSA forces load -> wait -> consume
#define WCVT(B, N) { \
  asm volatile("s_waitcnt vmcnt(" #N ")" : "+v"(B)); \
  acc[0] += __builtin_amdgcn_cvt_pk_f32_fp8(B[0], false); \
  acc[1] += __builtin_amdgcn_cvt_pk_f32_fp8(B[0], true);  \
  acc[2] += __builtin_amdgcn_cvt_pk_f32_fp8(B[1], false); \
  acc[3] += __builtin_amdgcn_cvt_pk_f32_fp8(B[1], true);  \
  acc[4] += __builtin_amdgcn_cvt_pk_f32_fp8(B[2], false); \
  acc[5] += __builtin_amdgcn_cvt_pk_f32_fp8(B[2], true);  \
  acc[6] += __builtin_amdgcn_cvt_pk_f32_fp8(B[3], false); \
  acc[7] += __builtin_amdgcn_cvt_pk_f32_fp8(B[3], true);  }

// ---- gather+mean: 32 nodes/block, 8-lane groups, 8-deep sc0 pipeline ----
__global__ __launch_bounds__(256) void gather_kernel(
    const uint8_t* __restrict__ xf8,
    const int* __restrict__ nbrs,
    const int* __restrict__ flag,
    uint16_t* __restrict__ agg)
{
  __shared__ int idxs[4][8 * KN];            // 6400 B
  const int tid  = threadIdx.x;
  const int wave = tid >> 6, lane = tid & 63;
  const int base = blockIdx.x * 32;          // 32 nodes per block, 8 per wave
  const int stride_mul = (*flag != 0) ? 1 : 2;

  // stage this wave's 8 rows x 50 neighbor indices
  {
    long long fb = (long long)(base + wave * 8) * KN;
    for (int t = lane; t < 8 * KN; t += 64)
      idxs[wave][t] = nbrs[(fb + t) * stride_mul];
  }
  __syncthreads();                           // drains vmcnt -> pipeline count clean

  const int g  = lane >> 3;                  // 8 groups of 8 lanes
  const int fl = (lane & 7) * 16;            // 16 fp8 features per lane
  const int node = base + wave * 8 + g;
  const int* ip = &idxs[wave][g * KN];
  const uint8_t* xfl = xf8 + fl;

  f32x2 acc[8];
  #pragma unroll
  for (int i = 0; i < 8; i++) acc[i] = (f32x2){0.f, 0.f};

  u32x4 b0, b1, b2, b3, b4, b5, b6, b7;
  GLOAD(b0, 0) GLOAD(b1, 1) GLOAD(b2, 2) GLOAD(b3, 3)
  GLOAD(b4, 4) GLOAD(b5, 5) GLOAD(b6, 6) GLOAD(b7, 7)

  #pragma unroll
  for (int t = 0; t < 5; ++t){
    const int k = t * 8;
    WCVT(b0, 7) GLOAD(b0, k + 8)
    WCVT(b1, 7) GLOAD(b1, k + 9)
    WCVT(b2, 7) GLOAD(b2, k + 10)
    WCVT(b3, 7) GLOAD(b3, k + 11)
    WCVT(b4, 7) GLOAD(b4, k + 12)
    WCVT(b5, 7) GLOAD(b5, k + 13)
    WCVT(b6, 7) GLOAD(b6, k + 14)
    WCVT(b7, 7) GLOAD(b7, k + 15)
  }
  // consumed 0..39, outstanding 40..47
  WCVT(b0, 7) GLOAD(b0, 48)
  WCVT(b1, 7) GLOAD(b1, 49)
  WCVT(b2, 7) WCVT(b3, 6) WCVT(b4, 5) WCVT(b5, 4)
  WCVT(b6, 3) WCVT(b7, 2) WCVT(b0, 1) WCVT(b1, 0)

  uint16_t o[16];
  #pragma unroll
  for (int i = 0; i < 8; i++){
    o[2*i]   = f2b(acc[i].x * (1.0f / KN));
    o[2*i+1] = f2b(acc[i].y * (1.0f / KN));
  }
  uint16_t* dst = agg + (size_t)node * FIN + fl;   // fl doubles as bf16 elem offset
  *(uint4*)(dst)     = *(const uint4*)(o);
  *(uint4*)(dst + 8) = *(const uint4*)(o + 8);
}

// ---- GEMM: concat(x, agg) @ W + b, relu ----
__global__ __launch_bounds__(256) void gemm_kernel(
    const float* __restrict__ x,
    const uint16_t* __restrict__ agg,
    const uint16_t* __restrict__ wp,
    const float* __restrict__ bias,
    float* __restrict__ out)
{
  __shared__ uint16_t h[BM][264];            // 33792 B
  const int tid  = threadIdx.x;
  const int wave = tid >> 6, lane = tid & 63;
  const int base = blockIdx.x * BM;

  // self features: x fp32 -> bf16 -> h[r][0..128)
  #pragma unroll
  for (int jj = 0; jj < 8; jj++){
    int ci = jj * 256 + tid;                 // 2048 float4 chunks
    int r = ci >> 5, c = ci & 31;
    int node = base + r; if (node >= NN) node = NN - 1;
    float4 v = *(const float4*)(x + (size_t)node * FIN + c * 4);
    ushort4 o2; o2.x = f2b(v.x); o2.y = f2b(v.y); o2.z = f2b(v.z); o2.w = f2b(v.w);
    *(ushort4*)(&h[r][c * 4]) = o2;
  }
  // aggregated features: bf16 copy -> h[r][128..256)
  #pragma unroll
  for (int jj = 0; jj < 4; jj++){
    int ci = jj * 256 + tid;                 // 1024 uint4 chunks
    int r = ci >> 4, c = ci & 15;
    int node = base + r; if (node >= NN) node = NN - 1;
    uint4 v = *(const uint4*)(agg + (size_t)node * FIN + c * 8);
    *(uint4*)(&h[r][FIN + c * 8]) = v;
  }

  // B fragments: wave w owns cols [w*32, w*32+32)
  bf16x8 bfr[8][2];
  #pragma unroll
  for (int kt = 0; kt < 8; kt++)
    #pragma unroll
    for (int ntl = 0; ntl < 2; ntl++){
      int nt = wave * 2 + ntl;
      bfr[kt][ntl] = *(const bf16x8*)(wp + ((size_t)(kt * 8 + nt) * 64 + lane) * 8);
    }

  __syncthreads();

  f32x4 acc[4][2];
  #pragma unroll
  for (int mt = 0; mt < 4; mt++)
    for (int n = 0; n < 2; n++) acc[mt][n] = (f32x4){0.f, 0.f, 0.f, 0.f};

  const int arow = lane & 15;
  const int ak   = (lane >> 4) << 3;
  #pragma unroll
  for (int kt = 0; kt < 8; kt++){
    #pragma unroll
    for (int mt = 0; mt < 4; mt++){
      bf16x8 af = *(const bf16x8*)(&h[mt * 16 + arow][kt * 32 + ak]);
      acc[mt][0] = __builtin_amdgcn_mfma_f32_16x16x32_bf16(af, bfr[kt][0], acc[mt][0], 0, 0, 0);
      acc[mt][1] = __builtin_amdgcn_mfma_f32_16x16x32_bf16(af, bfr[kt][1], acc[mt][1], 0, 0, 0);
    }
  }

  // epilogue: C/D layout col=lane&15, row=(lane>>4)*4+i  [m89]
  #pragma unroll
  for (int ntl = 0; ntl < 2; ntl++){
    int col = wave * 32 + ntl * 16 + (lane & 15);
    float bv = bias[col];
    #pragma unroll
    for (int mt = 0; mt < 4; mt++){
      #pragma unroll
      for (int i = 0; i < 4; i++){
        int row = mt * 16 + ((lane >> 4) << 2) + i;
        int node = base + row;
        if (node < NN){
          float v = acc[mt][ntl][i] + bv;
          out[(size_t)node * FOUT + col] = fmaxf(v, 0.f);
        }
      }
    }
  }
}

extern "C" void kernel_launch(void* const* d_in, const int* in_sizes, int n_in,
                              void* d_out, int out_size, void* d_ws, size_t ws_size,
                              hipStream_t stream){
  const float* x    = (const float*)d_in[0];
  const int*   nbrs = (const int*)d_in[1];
  const float* w    = (const float*)d_in[2];
  const float* bias = (const float*)d_in[3];
  float* out = (float*)d_out;

  uint8_t*  xf8  = (uint8_t*)d_ws;                                        // 12.8 MB
  uint16_t* wp   = (uint16_t*)((char*)d_ws + (size_t)NN * FIN);           // 64 KB
  int*      flag = (int*)((char*)d_ws + (size_t)NN * FIN + 65536);
  uint16_t* agg  = (uint16_t*)((char*)d_ws + (size_t)NN * FIN + 131072);  // 25.6 MB

  (void)hipMemsetAsync(flag, 0, 4, stream);
  cast_fp8_kernel<<<NN * FIN / 4 / 256, 256, 0, stream>>>(x, (uint32_t*)xf8);
  pack_w_kernel<<<64, 64, 0, stream>>>(w, wp);
  detect_kernel<<<32, 256, 0, stream>>>(nbrs, flag);
  gather_kernel<<<NN / 32, 256, 0, stream>>>(xf8, nbrs, flag, agg);
  gemm_kernel<<<(NN + BM - 1) / BM, 256, 0, stream>>>(x, agg, wp, bias, out);
}

// Round 12
// 123.141 us; speedup vs baseline: 2.5871x; 1.0015x over previous
//
#include <hip/hip_runtime.h>
#include <hip/hip_bf16.h>
#include <stdint.h>

#define NN 100000
#define KN 50
#define FIN 128
#define FOUT 128
#define BM 64

typedef __attribute__((ext_vector_type(8))) short bf16x8;
typedef __attribute__((ext_vector_type(4))) float f32x4;
typedef __attribute__((ext_vector_type(2))) float f32x2;

__device__ __forceinline__ uint16_t f2b(float f){
  uint32_t x = __builtin_bit_cast(uint32_t, f);
  x += 0x7fffu + ((x >> 16) & 1u);   // round-to-nearest-even
  return (uint16_t)(x >> 16);
}

// ---- prep: cast x fp32 -> fp8 e4m3 (HW cvt) for the gather path ----
__global__ void cast_fp8_kernel(const float* __restrict__ x, uint32_t* __restrict__ xf8){
  int i = blockIdx.x * blockDim.x + threadIdx.x;      // one u32 = 4 fp8
  float4 v = *(const float4*)(x + (size_t)i * 4);
  uint32_t p = 0;
  p = __builtin_amdgcn_cvt_pk_fp8_f32(v.x, v.y, p, false);
  p = __builtin_amdgcn_cvt_pk_fp8_f32(v.z, v.w, p, true);
  xf8[i] = p;
}

// ---- prep: pack weight [256][128] fp32 -> bf16 in MFMA B-fragment order ----
__global__ void pack_w_kernel(const float* __restrict__ w, uint16_t* __restrict__ wp){
  int kt = blockIdx.x >> 3, nt = blockIdx.x & 7;
  int lane = threadIdx.x;
  int col = nt * 16 + (lane & 15);
  int k0  = kt * 32 + ((lane >> 4) << 3);
  uint16_t vals[8];
  #pragma unroll
  for (int i = 0; i < 8; i++) vals[i] = f2b(w[(k0 + i) * FOUT + col]);
  *(uint4*)(wp + ((size_t)(kt * 8 + nt) * 64 + lane) * 8) = *(const uint4*)vals;
}

// ---- prep: detect int32 vs int64 neighbors layout (prefix scan is enough) ----
__global__ void detect_kernel(const int* __restrict__ nb, int* __restrict__ flag){
  int i = blockIdx.x * blockDim.x + threadIdx.x;   // 8192 odd words
  if (nb[2 * i + 1] != 0) *flag = 1;
}

#define CVT8(ACC, v)                                           \
  ACC[0] += __builtin_amdgcn_cvt_pk_f32_fp8((v).x, false);     \
  ACC[1] += __builtin_amdgcn_cvt_pk_f32_fp8((v).x, true);      \
  ACC[2] += __builtin_amdgcn_cvt_pk_f32_fp8((v).y, false);     \
  ACC[3] += __builtin_amdgcn_cvt_pk_f32_fp8((v).y, true);      \
  ACC[4] += __builtin_amdgcn_cvt_pk_f32_fp8((v).z, false);     \
  ACC[5] += __builtin_amdgcn_cvt_pk_f32_fp8((v).z, true);      \
  ACC[6] += __builtin_amdgcn_cvt_pk_f32_fp8((v).w, false);     \
  ACC[7] += __builtin_amdgcn_cvt_pk_f32_fp8((v).w, true);

// ---- fused gather+mean+GEMM: overlap GEMM compute inside the gather's
// request-meter stall shadow (request rate is the proven roofline; while one
// block's waves wait on random row-requests, co-resident blocks run MFMA).
__global__ __launch_bounds__(256, 4) void fused_kernel(
    const float* __restrict__ x,
    const uint8_t* __restrict__ xf8,
    const int* __restrict__ nbrs,
    const uint16_t* __restrict__ wp,
    const float* __restrict__ bias,
    const int* __restrict__ flag,
    float* __restrict__ out)
{
  __shared__ uint16_t h[BM][264];            // 33792 B total LDS
  int* idxs = (int*)&h[0][0];                // 12.8 KB aliased; dead before h is written
  const int tid  = threadIdx.x;
  const int wave = tid >> 6, lane = tid & 63;
  const int base = blockIdx.x * BM;
  const int sm = (*flag != 0) ? 1 : 2;       // int64: low dword at 2x index

  // phase 1: stage this wave's 16 rows x 50 neighbor indices
  {
    long long fb = (long long)(base + wave * 16) * KN;
    const long long fcap = (long long)NN * KN - 1;
    for (int t = lane; t < 16 * KN; t += 64){
      long long f = fb + t; if (f > fcap) f = fcap;   // clamp OOB rows
      idxs[wave * 16 * KN + t] = nbrs[f * sm];
    }
  }
  __syncthreads();

  // phase 2: gather. 8-lane groups; each group owns 2 rows (request-rate-bound).
  const int g  = lane >> 3;
  const int fl = (lane & 7) * 16;            // 16 fp8 features per lane
  const uint8_t* xfl = xf8 + fl;
  const int* ipA = idxs + wave * 16 * KN + g * KN;
  const int* ipB = ipA + 8 * KN;

  f32x2 accA[8], accB[8];
  #pragma unroll
  for (int i = 0; i < 8; i++){ accA[i] = (f32x2){0.f,0.f}; accB[i] = (f32x2){0.f,0.f}; }

  #pragma unroll 10
  for (int k = 0; k < KN; k++){
    int j = ipA[k];
    uint4 v = *(const uint4*)(xfl + ((size_t)(uint32_t)j << 7));
    CVT8(accA, v);
  }
  #pragma unroll 10
  for (int k = 0; k < KN; k++){
    int j = ipB[k];
    uint4 v = *(const uint4*)(xfl + ((size_t)(uint32_t)j << 7));
    CVT8(accB, v);
  }

  __syncthreads();                           // idxs region dead from here

  // phase 3a: dump agg (bf16) into h[r][128..256)
  {
    uint16_t oA[16], oB[16];
    #pragma unroll
    for (int i = 0; i < 8; i++){
      oA[2*i]   = f2b(accA[i].x * (1.0f / KN));
      oA[2*i+1] = f2b(accA[i].y * (1.0f / KN));
      oB[2*i]   = f2b(accB[i].x * (1.0f / KN));
      oB[2*i+1] = f2b(accB[i].y * (1.0f / KN));
    }
    uint16_t* dA = &h[wave * 16 + g][FIN + fl];
    uint16_t* dB = &h[wave * 16 + 8 + g][FIN + fl];
    *(uint4*)(dA)     = *(const uint4*)(oA);
    *(uint4*)(dA + 8) = *(const uint4*)(oA + 8);
    *(uint4*)(dB)     = *(const uint4*)(oB);
    *(uint4*)(dB + 8) = *(const uint4*)(oB + 8);
  }

  // phase 3b: self features x fp32 -> bf16 -> h[r][0..128) (cooperative)
  #pragma unroll
  for (int jj = 0; jj < 8; jj++){
    int ci = jj * 256 + tid;                 // 2048 float4 chunks
    int r = ci >> 5, c = ci & 31;
    int node = base + r; if (node >= NN) node = NN - 1;
    float4 v = *(const float4*)(x + (size_t)node * FIN + c * 4);
    ushort4 o2; o2.x = f2b(v.x); o2.y = f2b(v.y); o2.z = f2b(v.z); o2.w = f2b(v.w);
    *(ushort4*)(&h[r][c * 4]) = o2;
  }

  // phase 3c: B fragments (L2-hot): wave w owns cols [w*32, w*32+32)
  bf16x8 bfr[8][2];
  #pragma unroll
  for (int kt = 0; kt < 8; kt++)
    #pragma unroll
    for (int ntl = 0; ntl < 2; ntl++){
      int nt = wave * 2 + ntl;
      bfr[kt][ntl] = *(const bf16x8*)(wp + ((size_t)(kt * 8 + nt) * 64 + lane) * 8);
    }

  __syncthreads();

  // phase 4: GEMM, 64 MFMAs (16x16x32 bf16)
  f32x4 acc[4][2];
  #pragma unroll
  for (int mt = 0; mt < 4; mt++)
    for (int n = 0; n < 2; n++) acc[mt][n] = (f32x4){0.f, 0.f, 0.f, 0.f};

  const int arow = lane & 15;
  const int ak   = (lane >> 4) << 3;
  #pragma unroll
  for (int kt = 0; kt < 8; kt++){
    #pragma unroll
    for (int mt = 0; mt < 4; mt++){
      bf16x8 af = *(const bf16x8*)(&h[mt * 16 + arow][kt * 32 + ak]);
      acc[mt][0] = __builtin_amdgcn_mfma_f32_16x16x32_bf16(af, bfr[kt][0], acc[mt][0], 0, 0, 0);
      acc[mt][1] = __builtin_amdgcn_mfma_f32_16x16x32_bf16(af, bfr[kt][1], acc[mt][1], 0, 0, 0);
    }
  }

  // phase 5: epilogue. C/D layout col=lane&15, row=(lane>>4)*4+i  [m89]
  #pragma unroll
  for (int ntl = 0; ntl < 2; ntl++){
    int col = wave * 32 + ntl * 16 + (lane & 15);
    float bv = bias[col];
    #pragma unroll
    for (int mt = 0; mt < 4; mt++){
      #pragma unroll
      for (int i = 0; i < 4; i++){
        int row = mt * 16 + ((lane >> 4) << 2) + i;
        int node = base + row;
        if (node < NN){
          float v = acc[mt][ntl][i] + bv;
          out[(size_t)node * FOUT + col] = fmaxf(v, 0.f);
        }
      }
    }
  }
}

extern "C" void kernel_launch(void* const* d_in, const int* in_sizes, int n_in,
                              void* d_out, int out_size, void* d_ws, size_t ws_size,
                              hipStream_t stream){
  const float* x    = (const float*)d_in[0];
  const int*   nbrs = (const int*)d_in[1];
  const float* w    = (const float*)d_in[2];
  const float* bias = (const float*)d_in[3];
  float* out = (float*)d_out;

  uint8_t*  xf8  = (uint8_t*)d_ws;                                   // 12.8 MB
  uint16_t* wp   = (uint16_t*)((char*)d_ws + (size_t)NN * FIN);      // 64 KB
  int*      flag = (int*)((char*)d_ws + (size_t)NN * FIN + 65536);

  (void)hipMemsetAsync(flag, 0, 4, stream);
  cast_fp8_kernel<<<NN * FIN / 4 / 256, 256, 0, stream>>>(x, (uint32_t*)xf8);
  pack_w_kernel<<<64, 64, 0, stream>>>(w, wp);
  detect_kernel<<<32, 256, 0, stream>>>(nbrs, flag);
  fused_kernel<<<(NN + BM - 1) / BM, 256, 0, stream>>>(x, xf8, nbrs, wp, bias, flag, out);
}

// Round 13
// 104.203 us; speedup vs baseline: 3.0573x; 1.1817x over previous
//
#include <hip/hip_runtime.h>
#include <hip/hip_bf16.h>
#include <stdint.h>

#define NN 100000
#define KN 50
#define FIN 128
#define FOUT 128
#define BM 64
#define NCAST 12500          // NN*FIN/4/256
#define NPACK 16             // 4096 threads
#define NDET 32              // 8192 threads

typedef __attribute__((ext_vector_type(8))) short bf16x8;
typedef __attribute__((ext_vector_type(4))) float f32x4;
typedef __attribute__((ext_vector_type(2))) float f32x2;

__device__ __forceinline__ uint16_t f2b(float f){
  uint32_t x = __builtin_bit_cast(uint32_t, f);
  x += 0x7fffu + ((x >> 16) & 1u);   // round-to-nearest-even
  return (uint16_t)(x >> 16);
}

// ---- prep: cast x->fp8 | pack W->bf16 frags | detect idx layout, one launch ----
__global__ __launch_bounds__(256) void prep_kernel(
    const float* __restrict__ x, uint32_t* __restrict__ xf8,
    const float* __restrict__ w, uint16_t* __restrict__ wp,
    const int* __restrict__ nb, int* __restrict__ flag)
{
  const int b = blockIdx.x, tid = threadIdx.x;
  if (b < NCAST){
    int i = b * 256 + tid;                 // one u32 = 4 fp8
    float4 v = *(const float4*)(x + (size_t)i * 4);
    uint32_t p = 0;
    p = __builtin_amdgcn_cvt_pk_fp8_f32(v.x, v.y, p, false);
    p = __builtin_amdgcn_cvt_pk_fp8_f32(v.z, v.w, p, true);
    xf8[i] = p;
  } else if (b < NCAST + NPACK){
    int tp = (b - NCAST) * 256 + tid;      // 4096 = 64 tiles x 64 lanes
    int bb = tp >> 6, lane = tp & 63;
    int kt = bb >> 3, nt = bb & 7;
    int col = nt * 16 + (lane & 15);
    int k0  = kt * 32 + ((lane >> 4) << 3);
    uint16_t vals[8];
    #pragma unroll
    for (int i = 0; i < 8; i++) vals[i] = f2b(w[(k0 + i) * FOUT + col]);
    *(uint4*)(wp + ((size_t)(kt * 8 + nt) * 64 + lane) * 8) = *(const uint4*)vals;
  } else {
    int i = (b - NCAST - NPACK) * 256 + tid;   // 8192 odd words
    if (nb[2 * i + 1] != 0) *flag = 1;
  }
}

#define CVT8(ACC, v)                                           \
  ACC[0] += __builtin_amdgcn_cvt_pk_f32_fp8((v).x, false);     \
  ACC[1] += __builtin_amdgcn_cvt_pk_f32_fp8((v).x, true);      \
  ACC[2] += __builtin_amdgcn_cvt_pk_f32_fp8((v).y, false);     \
  ACC[3] += __builtin_amdgcn_cvt_pk_f32_fp8((v).y, true);      \
  ACC[4] += __builtin_amdgcn_cvt_pk_f32_fp8((v).z, false);     \
  ACC[5] += __builtin_amdgcn_cvt_pk_f32_fp8((v).z, true);      \
  ACC[6] += __builtin_amdgcn_cvt_pk_f32_fp8((v).w, false);     \
  ACC[7] += __builtin_amdgcn_cvt_pk_f32_fp8((v).w, true);

// ---- fused gather+mean+GEMM, 8 waves/block: 4 blocks/CU x 8 = 32 waves/CU ----
// Gather shape per wave == r4's proven-optimal (8 rows, 8-lane groups). GEMM
// runs in the gather stall shadow of co-resident blocks. VGPR forced <=64.
__global__ __launch_bounds__(512, 8) void fused_kernel(
    const float* __restrict__ x,
    const uint8_t* __restrict__ xf8,
    const int* __restrict__ nbrs,
    const uint16_t* __restrict__ wp,
    const float* __restrict__ bias,
    const int* __restrict__ flag,
    float* __restrict__ out)
{
  __shared__ uint16_t h[BM][264];            // 33792 B
  int* idxs = (int*)&h[0][0];                // 12.8 KB aliased; dead before h written
  const int tid  = threadIdx.x;
  const int wave = tid >> 6, lane = tid & 63;  // 8 waves
  const int base = blockIdx.x * BM;
  const int sm = (*flag != 0) ? 1 : 2;       // int64: low dword at 2x index

  // phase 1: each wave stages its 8 rows x 50 neighbor indices
  {
    long long fb = (long long)(base + wave * 8) * KN;
    const long long fcap = (long long)NN * KN - 1;
    for (int t = lane; t < 8 * KN; t += 64){
      long long f = fb + t; if (f > fcap) f = fcap;   // clamp OOB rows
      idxs[wave * 8 * KN + t] = nbrs[f * sm];
    }
  }
  __syncthreads();

  // phase 2: gather (request-rate-bound). 8-lane group g owns row wave*8+g.
  const int g  = lane >> 3;
  const int fl = (lane & 7) * 16;            // 16 fp8 features per lane
  const uint8_t* xfl = xf8 + fl;
  const int* ip = idxs + wave * 8 * KN + g * KN;

  f32x2 acc8[8];
  #pragma unroll
  for (int i = 0; i < 8; i++) acc8[i] = (f32x2){0.f, 0.f};

  #pragma unroll 10
  for (int k = 0; k < KN; k++){
    int j = ip[k];
    uint4 v = *(const uint4*)(xfl + ((size_t)(uint32_t)j << 7));
    CVT8(acc8, v);
  }

  __syncthreads();                           // idxs region dead from here

  // phase 3a: dump agg (bf16) into h[wave*8+g][128+fl..]
  {
    uint16_t o[16];
    #pragma unroll
    for (int i = 0; i < 8; i++){
      o[2*i]   = f2b(acc8[i].x * (1.0f / KN));
      o[2*i+1] = f2b(acc8[i].y * (1.0f / KN));
    }
    uint16_t* d = &h[wave * 8 + g][FIN + fl];
    *(uint4*)(d)     = *(const uint4*)(o);
    *(uint4*)(d + 8) = *(const uint4*)(o + 8);
  }

  // phase 3b: self features x fp32 -> bf16 -> h[r][0..128) (cooperative, 512 thr)
  #pragma unroll
  for (int jj = 0; jj < 4; jj++){
    int ci = jj * 512 + tid;                 // 2048 float4 chunks
    int r = ci >> 5, c = ci & 31;
    int node = base + r; if (node >= NN) node = NN - 1;
    float4 v = *(const float4*)(x + (size_t)node * FIN + c * 4);
    ushort4 o2; o2.x = f2b(v.x); o2.y = f2b(v.y); o2.z = f2b(v.z); o2.w = f2b(v.w);
    *(ushort4*)(&h[r][c * 4]) = o2;
  }

  __syncthreads();

  // phase 4: GEMM. Wave w owns 16 output cols (nt=w); B-frag loaded per kt
  // from L2-hot wp (saves ~28 VGPR -> stays under the 64-reg/8-wave cap).
  f32x4 acc[4];
  #pragma unroll
  for (int mt = 0; mt < 4; mt++) acc[mt] = (f32x4){0.f, 0.f, 0.f, 0.f};

  const int arow = lane & 15;
  const int ak   = (lane >> 4) << 3;
  #pragma unroll
  for (int kt = 0; kt < 8; kt++){
    bf16x8 bfrk = *(const bf16x8*)(wp + ((size_t)(kt * 8 + wave) * 64 + lane) * 8);
    #pragma unroll
    for (int mt = 0; mt < 4; mt++){
      bf16x8 af = *(const bf16x8*)(&h[mt * 16 + arow][kt * 32 + ak]);
      acc[mt] = __builtin_amdgcn_mfma_f32_16x16x32_bf16(af, bfrk, acc[mt], 0, 0, 0);
    }
  }

  // phase 5: epilogue. C/D layout col=lane&15, row=(lane>>4)*4+i  [m89]
  {
    int col = wave * 16 + (lane & 15);
    float bv = bias[col];
    #pragma unroll
    for (int mt = 0; mt < 4; mt++){
      #pragma unroll
      for (int i = 0; i < 4; i++){
        int row = mt * 16 + ((lane >> 4) << 2) + i;
        int node = base + row;
        if (node < NN){
          float v = acc[mt][i] + bv;
          out[(size_t)node * FOUT + col] = fmaxf(v, 0.f);
        }
      }
    }
  }
}

extern "C" void kernel_launch(void* const* d_in, const int* in_sizes, int n_in,
                              void* d_out, int out_size, void* d_ws, size_t ws_size,
                              hipStream_t stream){
  const float* x    = (const float*)d_in[0];
  const int*   nbrs = (const int*)d_in[1];
  const float* w    = (const float*)d_in[2];
  const float* bias = (const float*)d_in[3];
  float* out = (float*)d_out;

  uint8_t*  xf8  = (uint8_t*)d_ws;                                   // 12.8 MB
  uint16_t* wp   = (uint16_t*)((char*)d_ws + (size_t)NN * FIN);      // 64 KB
  int*      flag = (int*)((char*)d_ws + (size_t)NN * FIN + 65536);

  (void)hipMemsetAsync(flag, 0, 4, stream);
  prep_kernel<<<NCAST + NPACK + NDET, 256, 0, stream>>>(
      x, (uint32_t*)xf8, w, wp, (const int*)nbrs, flag);
  fused_kernel<<<(NN + BM - 1) / BM, 512, 0, stream>>>(
      x, xf8, nbrs, wp, bias, flag, out);
}